// Round 7
// baseline (423.167 us; speedup 1.0000x reference)
//
#include <hip/hip_runtime.h>

typedef unsigned short u16;
typedef unsigned int u32;
typedef __attribute__((ext_vector_type(8))) short bf16x8;
typedef __attribute__((ext_vector_type(4))) short bf16x4;
typedef __attribute__((ext_vector_type(4))) float f32x4;
typedef __attribute__((ext_vector_type(16))) float f32x16;

#define MFMA(a, b, c) __builtin_amdgcn_mfma_f32_16x16x32_bf16(a, b, c, 0, 0, 0)
#define MFMA32(a, b, c) __builtin_amdgcn_mfma_f32_32x32x16_bf16(a, b, c, 0, 0, 0)
#define ASYNC16(g, l)                                                        \
  __builtin_amdgcn_global_load_lds(                                          \
      (const __attribute__((address_space(1))) u32*)(g),                     \
      (__attribute__((address_space(3))) u32*)(l), 16, 0, 0)

#define SBARRIER()                                                           \
  do {                                                                       \
    asm volatile("" ::: "memory");                                           \
    __builtin_amdgcn_s_barrier();                                            \
    asm volatile("" ::: "memory");                                           \
  } while (0)

__device__ __forceinline__ float b2f(u16 u) {
  union { u32 i; float f; } x; x.i = ((u32)u) << 16; return x.f;
}
__device__ __forceinline__ u16 f2b(float f) {
  union { float f; u32 i; } x; x.f = f;
  return (u16)((x.i + 0x7fff + ((x.i >> 16) & 1)) >> 16);
}
__device__ __forceinline__ f32x4 fzero4() { f32x4 z = {0.f, 0.f, 0.f, 0.f}; return z; }
__device__ __forceinline__ f32x16 fzero16() {
  f32x16 z;
#pragma unroll
  for (int i = 0; i < 16; ++i) z[i] = 0.f;
  return z;
}
// v_cvt_pk_bf16_f32: dst.lo16 = bf16(lo), dst.hi16 = bf16(hi)
__device__ __forceinline__ u32 pkbf16(float lo, float hi) {
  u32 r;
  asm("v_cvt_pk_bf16_f32 %0, %1, %2" : "=v"(r) : "v"(lo), "v"(hi));
  return r;
}

// ---------------------------------------------------------------------------
// x fp32 [4096*2048] -> bf16
// ---------------------------------------------------------------------------
__global__ __launch_bounds__(256) void cvt_x(const float* __restrict__ src,
                                             u16* __restrict__ dst) {
  const int i = (blockIdx.x * 256 + threadIdx.x) * 4;
  const f32x4 v = *(const f32x4*)(src + i);
  bf16x4 o;
  o[0] = (short)f2b(v[0]); o[1] = (short)f2b(v[1]);
  o[2] = (short)f2b(v[2]); o[3] = (short)f2b(v[3]);
  *(bf16x4*)(dst + i) = o;
}

// ---------------------------------------------------------------------------
// Weight transpose + cast (single): W fp32 [K][N] -> WT bf16 [N][K].
// ---------------------------------------------------------------------------
__global__ __launch_bounds__(256) void wtrans_f32(const float* __restrict__ src,
                                                  u16* __restrict__ dst) {
  __shared__ u16 tile[64][65];
  const int k0 = blockIdx.y * 64, n0 = blockIdx.x * 64;
  const int t = threadIdx.x;
  const int tr = t >> 3, tc = t & 7;

#pragma unroll
  for (int hh = 0; hh < 2; ++hh) {
    const int k = tr + hh * 32;
    const float* p = src + (size_t)(k0 + k) * 2048 + n0 + tc * 8;
    const f32x4 a = *(const f32x4*)(p);
    const f32x4 b = *(const f32x4*)(p + 4);
#pragma unroll
    for (int j = 0; j < 4; ++j) tile[k][tc * 8 + j] = f2b(a[j]);
#pragma unroll
    for (int j = 0; j < 4; ++j) tile[k][tc * 8 + 4 + j] = f2b(b[j]);
  }
  __syncthreads();
#pragma unroll
  for (int hh = 0; hh < 2; ++hh) {
    const int n = tr + hh * 32;
    bf16x8 v;
#pragma unroll
    for (int j = 0; j < 8; ++j) v[j] = (short)tile[tc * 8 + j][n];
    *(bf16x8*)(dst + (size_t)(n0 + n) * 2048 + k0 + tc * 8) = v;
  }
}

// z-indexed variant: z=0,1,2 -> wq,wk,wv into wTall + z*2048*2048.
__global__ __launch_bounds__(256) void wtrans3(const float* __restrict__ wq,
                                               const float* __restrict__ wk,
                                               const float* __restrict__ wv,
                                               u16* __restrict__ wTall) {
  __shared__ u16 tile[64][65];
  const int z = blockIdx.z;
  const float* src = (z == 0) ? wq : (z == 1) ? wk : wv;
  u16* dst = wTall + (size_t)z * 2048 * 2048;
  const int k0 = blockIdx.y * 64, n0 = blockIdx.x * 64;
  const int t = threadIdx.x;
  const int tr = t >> 3, tc = t & 7;

#pragma unroll
  for (int hh = 0; hh < 2; ++hh) {
    const int k = tr + hh * 32;
    const float* p = src + (size_t)(k0 + k) * 2048 + n0 + tc * 8;
    const f32x4 a = *(const f32x4*)(p);
    const f32x4 b = *(const f32x4*)(p + 4);
#pragma unroll
    for (int j = 0; j < 4; ++j) tile[k][tc * 8 + j] = f2b(a[j]);
#pragma unroll
    for (int j = 0; j < 4; ++j) tile[k][tc * 8 + 4 + j] = f2b(b[j]);
  }
  __syncthreads();
#pragma unroll
  for (int hh = 0; hh < 2; ++hh) {
    const int n = tr + hh * 32;
    bf16x8 v;
#pragma unroll
    for (int j = 0; j < 8; ++j) v[j] = (short)tile[tc * 8 + j][n];
    *(bf16x8*)(dst + (size_t)(n0 + n) * 2048 + k0 + tc * 8) = v;
  }
}

// ---------------------------------------------------------------------------
// gemm_qkv9: x[4096,2048] @ wTall[6144,2048]^T -> Q/K/V.
// 256x256 tile (128 FLOP/staged-byte, 2x the 256x128 config), BK=32,
// 512 thr = 8 waves (2M x 4N, per-wave 128x64, acc[8][4]).
// Geometry (chunk-major LDS [kq][256][8], per-wave 128x64, scatter epilogue)
// field-proven by round-1's passing kernel; pipeline (ring-3 slots, stage t+2
// into t-1's dead slot, counted vmcnt, never 0 in-loop) proven by round-6.
// LDS: 3 slots x 32 KB = 96 KB.  4 stage-ops/step (A x2 in P1, B x2 in P2);
// boundary vmcnt(4) keeps t+2's 4 loads in flight while guaranteeing t+1.
// Compact XCD raster: xcd=orig&7 owns a 4m x 12n band -> first-round working
// set 4 A-panels + 8 B-panels per XCD (L3-resident, A reused across rounds).
// ---------------------------------------------------------------------------
__global__ __launch_bounds__(512, 2) void gemm_qkv9(const u16* __restrict__ x,
                                                    const u16* __restrict__ wT,
                                                    u16* __restrict__ qkv) {
  __shared__ u16 lds[3 * 16384];  // slot: A[4][256][8] + B[4][256][8] (32 KB)

  const int orig = blockIdx.x;           // 384 = 16m x 24n
  const int xcd = orig & 7, l = orig >> 3;             // l: 0..47
  const int m0 = ((xcd >> 1) * 4 + (l & 3)) * 256;     // m-tile 0..15
  const int n0 = ((xcd & 1) * 12 + (l >> 2)) * 256;    // n-tile 0..23

  const int tid = threadIdx.x;
  const int lane = tid & 63;
  const int wave = tid >> 6;
  const int quad = lane >> 4, l16 = lane & 15;
  const int wr = wave >> 2, wc = wave & 3;  // 2 x 4 wave grid, per-wave 128x64

  // staging: thread -> chunk (c = tid>>8, r = tid&255); linear LDS dest
  const int rs = tid & 255;
  const int cs = tid >> 8;  // 0..1 (op1 adds +2 chunks = +16 u16 global)
  const u16* gA = x + (size_t)(m0 + rs) * 2048 + cs * 8;
  const u16* gB = wT + (size_t)(n0 + rs) * 2048 + cs * 8;
  const int ldst = wave * 512;  // u16; HW adds lane*16B

#define SLOT9(t) (lds + ((t) % 3) * 16384)
#define STAGE_A9(t)                                                          \
  do {                                                                       \
    u16* d_ = SLOT9(t) + ldst;                                               \
    ASYNC16(gA + (t) * 32, d_);                                              \
    ASYNC16(gA + (t) * 32 + 16, d_ + 4096);                                  \
  } while (0)
#define STAGE_B9(t)                                                          \
  do {                                                                       \
    u16* d_ = SLOT9(t) + 8192 + ldst;                                        \
    ASYNC16(gB + (t) * 32, d_);                                              \
    ASYNC16(gB + (t) * 32 + 16, d_ + 4096);                                  \
  } while (0)

  f32x4 acc[8][4];
#pragma unroll
  for (int i = 0; i < 8; ++i)
#pragma unroll
    for (int j = 0; j < 4; ++j) acc[i][j] = fzero4();

  // fragment offsets (u16), chunk-major: chunk = quad plane of 2048 u16
  int aoff[8], boff[4];
#pragma unroll
  for (int mb = 0; mb < 8; ++mb)
    aoff[mb] = quad * 2048 + (wr * 128 + mb * 16 + l16) * 8;
#pragma unroll
  for (int nb = 0; nb < 4; ++nb)
    boff[nb] = 8192 + quad * 2048 + (wc * 64 + nb * 16 + l16) * 8;

  // prologue: stage tiles 0,1 (8 loads/thread); wait tile 0 (4 in flight)
  STAGE_A9(0); STAGE_B9(0);
  STAGE_A9(1); STAGE_B9(1);
  asm volatile("s_waitcnt vmcnt(4)" ::: "memory");
  SBARRIER();

  for (int t = 0; t < 64; ++t) {
    const u16* sl = SLOT9(t);
    bf16x8 af[4], bfr[4];

    // -------- phase 1: read A mb0-3 + B nb0-3; MFMA mb0-3 x nb0-3 --------
#pragma unroll
    for (int mb = 0; mb < 4; ++mb)
      af[mb] = *(const bf16x8*)(sl + aoff[mb]);
#pragma unroll
    for (int nb = 0; nb < 4; ++nb)
      bfr[nb] = *(const bf16x8*)(sl + boff[nb]);
    if (t < 62) STAGE_A9(t + 2);
    SBARRIER();
    asm volatile("s_waitcnt lgkmcnt(0)" ::: "memory");
    __builtin_amdgcn_s_setprio(1);
#pragma unroll
    for (int mb = 0; mb < 4; ++mb)
#pragma unroll
      for (int nb = 0; nb < 4; ++nb)
        acc[mb][nb] = MFMA(af[mb], bfr[nb], acc[mb][nb]);
    __builtin_amdgcn_s_setprio(0);
    SBARRIER();

    // -------- phase 2: read A mb4-7 (B reused); MFMA mb4-7 x nb0-3 --------
#pragma unroll
    for (int mb = 0; mb < 4; ++mb)
      af[mb] = *(const bf16x8*)(sl + aoff[mb + 4]);
    if (t < 62) STAGE_B9(t + 2);
    SBARRIER();
    asm volatile("s_waitcnt lgkmcnt(0)" ::: "memory");
    __builtin_amdgcn_s_setprio(1);
#pragma unroll
    for (int mb = 0; mb < 4; ++mb)
#pragma unroll
      for (int nb = 0; nb < 4; ++nb)
        acc[mb + 4][nb] = MFMA(af[mb], bfr[nb], acc[mb + 4][nb]);
    __builtin_amdgcn_s_setprio(0);
    // boundary: t+1 resident (oldest 4 drained), t+2's 4 stay in flight
    if (t <= 61) {
      asm volatile("s_waitcnt vmcnt(4)" ::: "memory");
    } else if (t == 62) {
      asm volatile("s_waitcnt vmcnt(0)" ::: "memory");
    }
    SBARRIER();
  }
#undef SLOT9
#undef STAGE_A9
#undef STAGE_B9

  // epilogue: scatter to Q/K/V layout [which][b*16+h][s][d] (round-1 proven)
  const size_t BUF = (size_t)4096 * 2048;
#pragma unroll
  for (int mb = 0; mb < 8; ++mb)
#pragma unroll
    for (int nb = 0; nb < 4; ++nb)
#pragma unroll
      for (int r = 0; r < 4; ++r) {
        const int row = m0 + wr * 128 + mb * 16 + quad * 4 + r;  // 0..4095
        const int col = n0 + wc * 64 + nb * 16 + l16;            // 0..6143
        const int b = row >> 11, s = row & 2047;
        const int which = col >> 11, rem = col & 2047;
        const int hh = rem >> 7, d = rem & 127;
        const size_t idx = (size_t)which * BUF +
                           (((size_t)(b * 16 + hh) * 2048 + s) * 128 + d);
        qkv[idx] = f2b(acc[mb][nb][r]);
      }
}

// ---------------------------------------------------------------------------
// gemm_out8: O[4096,2048] @ woT^T -> out fp32 (ring-3 pipeline, round-5 form).
// ---------------------------------------------------------------------------
__global__ __launch_bounds__(512, 2) void gemm_out8(const u16* __restrict__ Oin,
                                                    const u16* __restrict__ woT,
                                                    float* __restrict__ out) {
  __shared__ u16 lds[3 * 24576];

  const int orig = blockIdx.x;  // 256 blocks
  const int wg = (orig & 7) * 32 + (orig >> 3);
  const int m0 = (wg >> 4) * 256;
  const int n0 = (wg & 15) * 128;

  const int tid = threadIdx.x;
  const int lane = tid & 63;
  const int wave = tid >> 6;
  const int quad = lane >> 4, l16 = lane & 15;
  const int wr = wave >> 2, wc = wave & 3;

  const int r0s = tid >> 3;
  const int c0s = (tid & 7) ^ (r0s & 7);
  const int r1s = r0s + 64;
  const int c1s = (tid & 7) ^ (r1s & 7);

  const u16* gA = Oin + (size_t)m0 * 2048;
  const u16* gB = woT + (size_t)n0 * 2048;

#define SLOT8(t) (lds + ((t) % 3) * 24576)
#define STAGE_A8(t)                                                          \
  do {                                                                       \
    u16* Lb0 = SLOT8(t) + wave * 512;                                        \
    const u16* g0 = gA + (t) * 64;                                           \
    ASYNC16(g0 + (size_t)r0s * 2048 + c0s * 8, Lb0);                         \
    ASYNC16(g0 + (size_t)r1s * 2048 + c1s * 8, Lb0 + 4096);                  \
    u16* Lb1 = SLOT8(t) + 8192 + wave * 512;                                 \
    const u16* g1 = gA + (size_t)128 * 2048 + (t) * 64;                      \
    ASYNC16(g1 + (size_t)r0s * 2048 + c0s * 8, Lb1);                         \
    ASYNC16(g1 + (size_t)r1s * 2048 + c1s * 8, Lb1 + 4096);                  \
  } while (0)
#define STAGE_B8(t)                                                          \
  do {                                                                       \
    u16* Lb = SLOT8(t) + 16384 + wave * 512;                                 \
    const u16* g = gB + (t) * 64;                                            \
    ASYNC16(g + (size_t)r0s * 2048 + c0s * 8, Lb);                           \
    ASYNC16(g + (size_t)r1s * 2048 + c1s * 8, Lb + 4096);                    \
  } while (0)

  f32x4 acc[8][2];
#pragma unroll
  for (int i = 0; i < 8; ++i) { acc[i][0] = fzero4(); acc[i][1] = fzero4(); }

  int aoff[8], boff[2];
#pragma unroll
  for (int mb = 0; mb < 8; ++mb) aoff[mb] = (wr * 128 + mb * 16 + l16) * 64;
#pragma unroll
  for (int nb = 0; nb < 2; ++nb) boff[nb] = 16384 + (wc * 32 + nb * 16 + l16) * 64;
  const int ach0 = ((0 * 4 + quad) ^ (l16 & 7)) * 8;
  const int ach1 = ((1 * 4 + quad) ^ (l16 & 7)) * 8;

  STAGE_A8(0); STAGE_B8(0);
  STAGE_A8(1); STAGE_B8(1);
  asm volatile("s_waitcnt vmcnt(6)" ::: "memory");
  SBARRIER();

  for (int t = 0; t < 32; ++t) {
    const u16* sl = SLOT8(t);
    bf16x8 af[8], bfr[2];

#pragma unroll
    for (int mb = 0; mb < 8; ++mb)
      af[mb] = *(const bf16x8*)(sl + aoff[mb] + ach0);
#pragma unroll
    for (int nb = 0; nb < 2; ++nb)
      bfr[nb] = *(const bf16x8*)(sl + boff[nb] + ach0);
    if (t < 30) STAGE_A8(t + 2);
    SBARRIER();
    asm volatile("s_waitcnt lgkmcnt(0)" ::: "memory");
    __builtin_amdgcn_s_setprio(1);
#pragma unroll
    for (int mb = 0; mb < 8; ++mb)
#pragma unroll
      for (int nb = 0; nb < 2; ++nb)
        acc[mb][nb] = MFMA(af[mb], bfr[nb], acc[mb][nb]);
    __builtin_amdgcn_s_setprio(0);
    SBARRIER();

#pragma unroll
    for (int mb = 0; mb < 8; ++mb)
      af[mb] = *(const bf16x8*)(sl + aoff[mb] + ach1);
#pragma unroll
    for (int nb = 0; nb < 2; ++nb)
      bfr[nb] = *(const bf16x8*)(sl + boff[nb] + ach1);
    if (t < 30) STAGE_B8(t + 2);
    SBARRIER();
    asm volatile("s_waitcnt lgkmcnt(0)" ::: "memory");
    __builtin_amdgcn_s_setprio(1);
#pragma unroll
    for (int mb = 0; mb < 8; ++mb)
#pragma unroll
      for (int nb = 0; nb < 2; ++nb)
        acc[mb][nb] = MFMA(af[mb], bfr[nb], acc[mb][nb]);
    __builtin_amdgcn_s_setprio(0);
    if (t <= 29) {
      asm volatile("s_waitcnt vmcnt(6)" ::: "memory");
    } else if (t == 30) {
      asm volatile("s_waitcnt vmcnt(0)" ::: "memory");
    }
    SBARRIER();
  }
#undef SLOT8
#undef STAGE_A8
#undef STAGE_B8

#pragma unroll
  for (int mb = 0; mb < 8; ++mb)
#pragma unroll
    for (int nb = 0; nb < 2; ++nb)
#pragma unroll
      for (int r = 0; r < 4; ++r) {
        const int row = m0 + wr * 128 + mb * 16 + quad * 4 + r;
        const int col = n0 + wc * 32 + nb * 16 + l16;
        out[(size_t)row * 2048 + col] = acc[mb][nb][r];
      }
}

// ---------------------------------------------------------------------------
// RoPE in place on Q and K; folds 1/sqrt(128) into Q.
// ---------------------------------------------------------------------------
__global__ __launch_bounds__(256) void rope_kernel(u16* __restrict__ Q,
                                                   u16* __restrict__ K,
                                                   const float* __restrict__ fcos,
                                                   const float* __restrict__ fsin) {
  const int i = blockIdx.x * 256 + threadIdx.x;
  const int d = i & 63;
  const int s = (i >> 6) & 2047;
  const int bh = i >> 17;
  const size_t base = ((size_t)bh * 2048 + s) * 128;
  const float c = fcos[s * 64 + d];
  const float sn = fsin[s * 64 + d];
  const float qs = 0.08838834764831845f;

  const float q0 = b2f(Q[base + d]), q1 = b2f(Q[base + d + 64]);
  Q[base + d] = f2b((q0 * c - q1 * sn) * qs);
  Q[base + d + 64] = f2b((q1 * c + q0 * sn) * qs);
  const float k0 = b2f(K[base + d]), k1 = b2f(K[base + d + 64]);
  K[base + d] = f2b(k0 * c - k1 * sn);
  K[base + d + 64] = f2b(k1 * c + k0 * sn);
}

// ---------------------------------------------------------------------------
// Flash attention v4 (round-5 form: T13 defer-rescale + T5 setprio).
// ---------------------------------------------------------------------------
// S^T C-layout (32x32): col = lane&31 = q, row(reg,hi) = (r&3)+8*(r>>2)+4*hi.
template <int NB>
__device__ __forceinline__ void qkt_block(f32x16& sv, int n0, int qlo, int hi,
                                          int c, const u16* lK,
                                          const bf16x8* qf) {
  const int lo = n0 + NB * 32;
  if (lo < qlo + 32) {
    sv = fzero16();
    __builtin_amdgcn_s_setprio(1);
#pragma unroll
    for (int kc = 0; kc < 8; ++kc) {
      const bf16x8 kf =
          *(const bf16x8*)(lK + (NB * 32 + c) * 136 + kc * 16 + hi * 8);
      sv = MFMA32(kf, qf[kc], sv);
    }
    __builtin_amdgcn_s_setprio(0);
    if (lo == qlo) {  // diagonal 32x32: mask n32 > q32
#pragma unroll
      for (int r = 0; r < 16; ++r) {
        const int n32 = (r & 3) + 8 * (r >> 2) + 4 * hi;
        if (n32 > c) sv[r] = -1e30f;
      }
    }
  } else {
#pragma unroll
    for (int r = 0; r < 16; ++r) sv[r] = -1e30f;
  }
}

template <int NB>
__device__ __forceinline__ void pv_block(const f32x16& sv, int n0, int qlo,
                                         int hi, int c, const u16* lV,
                                         f32x16* accO) {
  if (n0 + NB * 32 < qlo + 32) {
#pragma unroll
    for (int half = 0; half < 2; ++half) {
      const int rb = half * 8;
      const u32 pA = pkbf16(sv[rb + 0], sv[rb + 1]);
      const u32 pB = pkbf16(sv[rb + 2], sv[rb + 3]);
      const u32 pC = pkbf16(sv[rb + 4], sv[rb + 5]);
      const u32 pD = pkbf16(sv[rb + 6], sv[rb + 7]);
      const u32 xA = (u32)__shfl_xor((int)pA, 32);
      const u32 xB = (u32)__shfl_xor((int)pB, 32);
      const u32 xC = (u32)__shfl_xor((int)pC, 32);
      const u32 xD = (u32)__shfl_xor((int)pD, 32);
      bf16x8 pa;
      u32* pw = (u32*)&pa;
      pw[0] = hi ? xC : pA;
      pw[1] = hi ? xD : pB;
      pw[2] = hi ? pC : xA;
      pw[3] = hi ? pD : xB;
      __builtin_amdgcn_s_setprio(1);
#pragma unroll
      for (int db = 0; db < 4; ++db) {
        const bf16x8 vf = *(const bf16x8*)(lV + (db * 32 + c) * 72 +
                                           NB * 32 + half * 16 + hi * 8);
        accO[db] = MFMA32(pa, vf, accO[db]);
      }
      __builtin_amdgcn_s_setprio(0);
    }
  }
}

__global__ __launch_bounds__(256, 2) void attn4(const u16* __restrict__ Q,
                                                const u16* __restrict__ K,
                                                const u16* __restrict__ V,
                                                u16* __restrict__ O) {
  __shared__ u16 lK[64 * 136];   // K-tile [n][d], stride 272B (odd x16B)
  __shared__ u16 lV[128 * 72];   // V^T    [d][n], stride 144B (odd x16B)

  const int bid = blockIdx.x;
  const int bh = (bid & 7) + 8 * ((bid >> 3) & 3);  // head-group per XCD
  const int tq = bid >> 5;
  const int qt = (tq < 8) ? tq : 23 - tq;           // pair: per-CU 34 iters
  const int q0 = qt * 128;
  const int b = bh >> 4, h = bh & 15;
  const u16* Qh = Q + (size_t)bh * 2048 * 128;
  const u16* Kh = K + (size_t)bh * 2048 * 128;
  const u16* Vh = V + (size_t)bh * 2048 * 128;

  const int tid = threadIdx.x;
  const int lane = tid & 63, wave = tid >> 6;
  const int hi = lane >> 5, c = lane & 31;
  const int qlo = q0 + wave * 32;
  const int krow = tid >> 4, kj = tid & 15;
  const int r0 = (tid & 31) * 2, d0v = (tid >> 5) * 16;

  // Q fragments (B-operand): lane holds Q[q0+wave*32+c][kc*16 + hi*8 + j]
  bf16x8 qf[8];
  {
    const u16* qrow = Qh + (size_t)(q0 + wave * 32 + c) * 128 + hi * 8;
#pragma unroll
    for (int kc = 0; kc < 8; ++kc) qf[kc] = *(const bf16x8*)(qrow + kc * 16);
  }

  float m_i = -1e30f, l_i = 0.f;
  f32x16 accO[4];
#pragma unroll
  for (int db = 0; db < 4; ++db) accO[db] = fzero16();

  const int nIter = 2 * qt + 2;

  bf16x8 kreg[4], vreg[4];
  {
#pragma unroll
    for (int i = 0; i < 4; ++i)
      kreg[i] = *(const bf16x8*)(Kh + (size_t)(krow + 16 * i) * 128 + kj * 8);
    const u16* vp = Vh + (size_t)r0 * 128 + d0v;
    vreg[0] = *(const bf16x8*)(vp);
    vreg[1] = *(const bf16x8*)(vp + 8);
    vreg[2] = *(const bf16x8*)(vp + 128);
    vreg[3] = *(const bf16x8*)(vp + 136);
  }

  for (int it = 0; it < nIter; ++it) {
    const int n0 = it * 64;
#pragma unroll
    for (int i = 0; i < 4; ++i)
      *(bf16x8*)(lK + (krow + 16 * i) * 136 + kj * 8) = kreg[i];
#pragma unroll
    for (int j = 0; j < 8; ++j) {
      const u32 lo = (u16)vreg[0][j], hi2 = (u16)vreg[2][j];
      *(u32*)(lV + (d0v + j) * 72 + r0) = lo | (hi2 << 16);
    }
#pragma unroll
    for (int j = 0; j < 8; ++j) {
      const u32 lo = (u16)vreg[1][j], hi2 = (u16)vreg[3][j];
      *(u32*)(lV + (d0v + 8 + j) * 72 + r0) = lo | (hi2 << 16);
    }
    __syncthreads();

    if (it + 1 < nIter) {
      const int nn = n0 + 64;
#pragma unroll
      for (int i = 0; i < 4; ++i)
        kreg[i] =
            *(const bf16x8*)(Kh + (size_t)(nn + krow + 16 * i) * 128 + kj * 8);
      const u16* vp = Vh + (size_t)(nn + r0) * 128 + d0v;
      vreg[0] = *(const bf16x8*)(vp);
      vreg[1] = *(const bf16x8*)(vp + 8);
      vreg[2] = *(const bf16x8*)(vp + 128);
      vreg[3] = *(const bf16x8*)(vp + 136);
    }

    f32x16 s0, s1;
    qkt_block<0>(s0, n0, qlo, hi, c, lK, qf);
    qkt_block<1>(s1, n0, qlo, hi, c, lK, qf);

    float mx = -1e30f;
#pragma unroll
    for (int r = 0; r < 16; ++r) mx = fmaxf(mx, fmaxf(s0[r], s1[r]));
    mx = fmaxf(mx, __shfl_xor(mx, 32));
    // T13 defer-rescale: skip O-rescale while max growth <= 8
    if (!__all(mx - m_i <= 8.0f)) {
      const float mn = fmaxf(m_i, mx);
      const float alpha = __expf(m_i - mn);
      m_i = mn;
      l_i *= alpha;
#pragma unroll
      for (int r = 0; r < 16; ++r) {
        const int src = ((r & 3) + 8 * (r >> 2) + 4 * hi) + (lane & 32);
        const float aa = __shfl(alpha, src);
        accO[0][r] *= aa; accO[1][r] *= aa;
        accO[2][r] *= aa; accO[3][r] *= aa;
      }
    }
    float rs = 0.f;
#pragma unroll
    for (int r = 0; r < 16; ++r) {
      const float p0 = __expf(s0[r] - m_i);
      const float p1 = __expf(s1[r] - m_i);
      s0[r] = p0; s1[r] = p1;
      rs += p0 + p1;
    }
    rs += __shfl_xor(rs, 32);
    l_i += rs;

    pv_block<0>(s0, n0, qlo, hi, c, lV, accO);
    pv_block<1>(s1, n0, qlo, hi, c, lV, accO);
    __syncthreads();
  }

  const float linv = 1.f / l_i;
#pragma unroll
  for (int r = 0; r < 16; ++r) {
    const int q32 = (r & 3) + 8 * (r >> 2) + 4 * hi;
    const float inv = __shfl(linv, q32 + (lane & 32));
    const int srow = q0 + wave * 32 + q32;
    u16* orow = O + ((size_t)b * 2048 + srow) * 2048 + h * 128 + c;
#pragma unroll
    for (int db = 0; db < 4; ++db) orow[db * 32] = f2b(accO[db][r] * inv);
  }
}

// ---------------------------------------------------------------------------
// Workspace (64 MiB): B0 = xb -> Ob alias, B1=Qb, B2=Kb, B3=Vb.
// wq/wk/wv transposed (25.2 MB) live in d_out (33.5 MB fp32, overwritten by
// gemm_out8 at the end); woT in Kb (dead after attn).
// ---------------------------------------------------------------------------
extern "C" void kernel_launch(void* const* d_in, const int* in_sizes, int n_in,
                              void* d_out, int out_size, void* d_ws, size_t ws_size,
                              hipStream_t stream) {
  const float* x  = (const float*)d_in[0];
  const float* fc = (const float*)d_in[1];
  const float* fs = (const float*)d_in[2];
  const float* wq = (const float*)d_in[3];
  const float* wk = (const float*)d_in[4];
  const float* wv = (const float*)d_in[5];
  const float* wo = (const float*)d_in[6];
  float* out = (float*)d_out;

  u16* ws = (u16*)d_ws;
  const size_t BUF = (size_t)4096 * 2048;
  u16* xb  = ws;
  u16* Ob  = ws;            // reuse B0 (xb dead after gemm_qkv9)
  u16* Qb  = ws + 1 * BUF;
  u16* Kb  = ws + 2 * BUF;
  u16* Vb  = ws + 3 * BUF;
  u16* wTall = (u16*)d_out; // 6144*2048 bf16 = 25.2 MB scratch in d_out
  u16* woT = Kb;            // wo transpose (Kb dead after attn)

  hipLaunchKernelGGL(cvt_x, dim3(8192), dim3(256), 0, stream, x, xb);
  hipLaunchKernelGGL(wtrans3, dim3(32, 32, 3), dim3(256), 0, stream, wq, wk, wv, wTall);
  hipLaunchKernelGGL(gemm_qkv9, dim3(384), dim3(512), 0, stream, xb, wTall, Qb);
  hipLaunchKernelGGL(rope_kernel, dim3(16384), dim3(256), 0, stream, Qb, Kb, fc, fs);
  hipLaunchKernelGGL(attn4, dim3(512), dim3(256), 0, stream, Qb, Kb, Vb, Ob);
  hipLaunchKernelGGL(wtrans_f32, dim3(32, 32), dim3(256), 0, stream, wo, woT);
  hipLaunchKernelGGL(gemm_out8, dim3(256), dim3(512), 0, stream, Ob, woT, out);
}